// Round 1
// baseline (16413.989 us; speedup 1.0000x reference)
//
#include <hip/hip_runtime.h>
#include <stdint.h>

// B=32, S=512, I=H=O=1024, L=2.  All inputs f32; compute in bf16 MFMA + f32 accum.

typedef __bf16 bf16x8 __attribute__((ext_vector_type(8)));
typedef float f32x4 __attribute__((ext_vector_type(4)));
typedef unsigned short u16;
typedef unsigned int u32;

typedef __attribute__((address_space(1))) u32 as1_u32;
typedef __attribute__((address_space(3))) u32 as3_u32;

__device__ __forceinline__ u16 f2bf(float f) {
  union { float f; u32 u; } a; a.f = f;
  u32 u = a.u;
  u32 r = (u + 0x7fffu + ((u >> 16) & 1u)) >> 16;  // RNE
  return (u16)r;
}
__device__ __forceinline__ float bf2f(u16 b) {
  union { u32 u; float f; } a; a.u = ((u32)b) << 16;
  return a.f;
}
__device__ __forceinline__ float sigmoidf_(float x) {
  return 1.0f / (1.0f + __expf(-x));
}
__device__ __forceinline__ bf16x8 as_bf(uint4 q) {
  union { uint4 q; bf16x8 v; } u; u.q = q; return u.v;
}

#define MFMA16(a, b, c) __builtin_amdgcn_mfma_f32_16x16x32_bf16((a), (b), (c), 0, 0, 0)

// async global->LDS, 16B per lane; lds dest = wave-uniform base + lane*16
__device__ __forceinline__ void gll16(const void* g, void* l) {
  __builtin_amdgcn_global_load_lds((as1_u32*)g, (as3_u32*)l, 16, 0, 0);
}

// ---------------- inter-workgroup epoch barrier (split arrive/wait) ----------------
__device__ __forceinline__ void bar_arrive(int* cnt) {
  __syncthreads();  // all wg writes done (compiler drains vmcnt before s_barrier)
  if (threadIdx.x == 0) {
    __builtin_amdgcn_fence(__ATOMIC_RELEASE, "agent");
    __hip_atomic_fetch_add(cnt, 1, __ATOMIC_RELAXED, __HIP_MEMORY_SCOPE_AGENT);
  }
}
__device__ __forceinline__ void bar_wait(int* cnt, int target) {
  if (threadIdx.x == 0) {
    while (__hip_atomic_load(cnt, __ATOMIC_RELAXED, __HIP_MEMORY_SCOPE_AGENT) < target)
      __builtin_amdgcn_s_sleep(2);
    __builtin_amdgcn_fence(__ATOMIC_ACQUIRE, "agent");
  }
  __syncthreads();
}

// Stage a [32][1024] bf16 matrix (64 KB) global->LDS.
// LDS holds 16B-chunk-swizzled layout: LDS chunk (row, sc) <- global chunk (row, sc ^ (row&7)).
__device__ __forceinline__ void stage32x1024(const u16* g, u16* lds, int tid) {
  const int lane = tid & 63, wv = tid >> 6;
#pragma unroll
  for (int it = 0; it < 16; ++it) {
    int base = wv * 1024 + it * 64;  // chunk index for lane 0 (wave-uniform)
    int ub = __builtin_amdgcn_readfirstlane(base);
    int c = base + lane;
    int row = c >> 7, sc = c & 127;
    int gsc = sc ^ (row & 7);
    gll16((const char*)g + (size_t)(row * 128 + gsc) * 16, (char*)lds + (size_t)ub * 16);
  }
}
// read one MFMA A-fragment (16B) for logical (row, chunk cc=kt*4+hi4) from swizzled LDS
__device__ __forceinline__ uint4 read_frag_sw(const u16* lds, int row, int kt, int hi4) {
  int cc = kt * 4 + hi4;
  int sc = cc ^ (row & 7);
  return *(const uint4*)((const char*)lds + (size_t)row * 2048 + (size_t)sc * 16);
}

// ---------------- persistent GRU recurrence (one layer, 512 steps) ----------------
// grid = 48 wg x 256 thr.  wave gw = wg*4+wv in [0,192): Wh row slice [gw*16, gw*16+16).
//   gw <  64 : z-gates (Wh rows    0..1023)
//   gw < 128 : r-gates (Wh rows 1024..2047)
//   gw < 192 : g-gates (Wh rows 2048..3071)   (wg 32..47)
// Per step: phase1 (zr wgs): pre = h @ Whzr^T; z->z_f32, rh=r*h -> rh_bf.  arrive A.
//           phase2 (g wgs):  wait A; pre = rh @ Whg^T; h_new -> h_f32/h_bf/ys. arrive B.
//           zr wgs wait B before next step.
__global__ __launch_bounds__(256, 1) void gru_rec_kernel(
    const u16* __restrict__ xproj,  // [512][32][3072] bf16
    const u16* __restrict__ Whl,    // [3072][1024] bf16 (this layer)
    u16* __restrict__ h_bf,         // [32][1024]
    float* __restrict__ h_f32,      // [32][1024]
    u16* __restrict__ rh_bf,        // [32][1024]
    float* __restrict__ z_f32,      // [32][1024]
    u16* __restrict__ ys,           // [32][512][1024]
    float* __restrict__ hidden,     // [32][2][1024] (d_out tail)
    int layer,
    int* __restrict__ bar)          // bar[0]=cntA, bar[16]=cntB (pre-zeroed)
{
  __shared__ u16 smem[32 * 1024];  // 64 KB staging (h or rh)
  const int tid = threadIdx.x;
  const int lane = tid & 63;
  const int wv = tid >> 6;
  const int wg = (int)blockIdx.x;
  const int gw = wg * 4 + wv;
  const bool is_g = (wg >= 32);
  const int col = lane & 15;       // output gate-column within 16-slice / A row
  const int hi4 = lane >> 4;       // 0..3
  const int n_g = gw * 16 + col;   // global gate index in [0,3072)

  // persistent B fragments: 32 k-iters x 16B = 128 VGPRs
  uint4 Bf[32];
  {
    const u16* wrow = Whl + (size_t)(gw * 16 + col) * 1024 + 8 * hi4;
#pragma unroll
    for (int kt = 0; kt < 32; ++kt) Bf[kt] = *(const uint4*)(wrow + kt * 32);
  }

  int* cntA = bar;
  int* cntB = bar + 16;

  for (int s = 0; s < 512; ++s) {
    // prefetch this step's xproj additive terms (read-only, safe any time)
    float xpv[8];
    {
      const u16* xb = xproj + (size_t)s * (32 * 3072) + n_g;
#pragma unroll
      for (int r = 0; r < 8; ++r) {
        int b = hi4 * 4 + (r & 3) + (r >> 2) * 16;
        xpv[r] = bf2f(xb[(size_t)b * 3072]);
      }
    }

    if (!is_g) {
      // ---- phase 1: z and r ----
      stage32x1024(h_bf, smem, tid);
      __syncthreads();
      f32x4 acc0 = {0.f, 0.f, 0.f, 0.f}, acc1 = {0.f, 0.f, 0.f, 0.f};
#pragma unroll
      for (int kt = 0; kt < 32; ++kt) {
        bf16x8 b = as_bf(Bf[kt]);
        uint4 a0 = read_frag_sw(smem, col, kt, hi4);
        uint4 a1 = read_frag_sw(smem, col + 16, kt, hi4);
        acc0 = MFMA16(as_bf(a0), b, acc0);
        acc1 = MFMA16(as_bf(a1), b, acc1);
      }
      if (gw < 64) {
#pragma unroll
        for (int r = 0; r < 8; ++r) {
          int b = hi4 * 4 + (r & 3) + (r >> 2) * 16;
          float pre = (r < 4) ? acc0[r & 3] : acc1[r & 3];
          z_f32[b * 1024 + n_g] = sigmoidf_(xpv[r] + pre);
        }
      } else {
        int rc = n_g - 1024;
#pragma unroll
        for (int r = 0; r < 8; ++r) {
          int b = hi4 * 4 + (r & 3) + (r >> 2) * 16;
          float pre = (r < 4) ? acc0[r & 3] : acc1[r & 3];
          float rv = sigmoidf_(xpv[r] + pre);
          rh_bf[b * 1024 + rc] = f2bf(rv * h_f32[b * 1024 + rc]);
        }
      }
      bar_arrive(cntA);
      bar_wait(cntB, 16 * (s + 1));
    } else {
      // ---- phase 2: g and h-update ----
      bar_wait(cntA, 32 * (s + 1));
      stage32x1024(rh_bf, smem, tid);
      __syncthreads();
      f32x4 acc0 = {0.f, 0.f, 0.f, 0.f}, acc1 = {0.f, 0.f, 0.f, 0.f};
#pragma unroll
      for (int kt = 0; kt < 32; ++kt) {
        bf16x8 b = as_bf(Bf[kt]);
        uint4 a0 = read_frag_sw(smem, col, kt, hi4);
        uint4 a1 = read_frag_sw(smem, col + 16, kt, hi4);
        acc0 = MFMA16(as_bf(a0), b, acc0);
        acc1 = MFMA16(as_bf(a1), b, acc1);
      }
      int gc = n_g - 2048;
#pragma unroll
      for (int r = 0; r < 8; ++r) {
        int b = hi4 * 4 + (r & 3) + (r >> 2) * 16;
        float pre = (r < 4) ? acc0[r & 3] : acc1[r & 3];
        float gv = sigmoidf_(xpv[r] + pre);
        float zv = z_f32[b * 1024 + gc];
        float ho = h_f32[b * 1024 + gc];
        float hn = zv * ho + (1.0f - zv) * gv;
        h_f32[b * 1024 + gc] = hn;
        u16 hb = f2bf(hn);
        h_bf[b * 1024 + gc] = hb;
        ys[(size_t)b * (512 * 1024) + (size_t)s * 1024 + gc] = hb;
        if (s == 511) hidden[b * 2048 + layer * 1024 + gc] = hn;
      }
      bar_arrive(cntB);
    }
  }
}

// ---------------- 128x128-tile bf16 GEMM: C[m,n] = sum_k A[m,k]*W[n,k] + bias[n] ----------------
// MODE 0: bf16 out to xproj layout [s][b][3072] with m = b*512+s
// MODE 1: f32 out, linear [m][N]
template <int MODE>
__global__ __launch_bounds__(256, 1) void gemm_bt_kernel(
    const u16* __restrict__ A, const u16* __restrict__ W,
    const float* __restrict__ bias, void* __restrict__ out,
    int M, int N, int K)
{
  __shared__ u16 At[128 * 32];
  __shared__ u16 Wt[128 * 32];
  const int tid = threadIdx.x;
  const int lane = tid & 63, wv = tid >> 6;
  const int wr = wv >> 1, wc = wv & 1;
  const int m0 = (int)blockIdx.y * 128, n0 = (int)blockIdx.x * 128;
  const int col = lane & 15, hi4 = lane >> 4;
  const size_t K2 = (size_t)K * 2;

  f32x4 acc[4][4];
#pragma unroll
  for (int i = 0; i < 4; ++i)
#pragma unroll
    for (int j = 0; j < 4; ++j) acc[i][j] = (f32x4){0.f, 0.f, 0.f, 0.f};

  const int nkt = K >> 5;
  for (int kt = 0; kt < nkt; ++kt) {
    __syncthreads();
#pragma unroll
    for (int it = 0; it < 2; ++it) {
      int cb = wv * 128 + it * 64;
      int ub = __builtin_amdgcn_readfirstlane(cb);
      int c = cb + lane;
      int row = c >> 2, slot = c & 3;
      int koff = (slot ^ ((row >> 1) & 3)) * 16;  // swizzled source -> linear LDS
      gll16((const char*)A + (size_t)(m0 + row) * K2 + (size_t)kt * 64 + koff,
            (char*)At + (size_t)ub * 16);
      gll16((const char*)W + (size_t)(n0 + row) * K2 + (size_t)kt * 64 + koff,
            (char*)Wt + (size_t)ub * 16);
    }
    __syncthreads();
    uint4 Af[4], Wf[4];
#pragma unroll
    for (int i = 0; i < 4; ++i) {
      int row = wr * 64 + i * 16 + col;
      int sc = hi4 ^ ((row >> 1) & 3);
      Af[i] = *(const uint4*)((const char*)At + (size_t)row * 64 + (size_t)sc * 16);
    }
#pragma unroll
    for (int j = 0; j < 4; ++j) {
      int row = wc * 64 + j * 16 + col;
      int sc = hi4 ^ ((row >> 1) & 3);
      Wf[j] = *(const uint4*)((const char*)Wt + (size_t)row * 64 + (size_t)sc * 16);
    }
#pragma unroll
    for (int i = 0; i < 4; ++i)
#pragma unroll
      for (int j = 0; j < 4; ++j)
        acc[i][j] = MFMA16(as_bf(Af[i]), as_bf(Wf[j]), acc[i][j]);
  }
  // epilogue: D[row=4*hi4+jj][col] per 16x16
#pragma unroll
  for (int i = 0; i < 4; ++i) {
#pragma unroll
    for (int j = 0; j < 4; ++j) {
      int n = n0 + wc * 64 + j * 16 + col;
      float bv = bias[n];
#pragma unroll
      for (int jj = 0; jj < 4; ++jj) {
        int m = m0 + wr * 64 + i * 16 + hi4 * 4 + jj;
        float v = acc[i][j][jj] + bv;
        if (MODE == 0) {
          ((u16*)out)[(size_t)(m & 511) * (32 * 3072) + (size_t)(m >> 9) * 3072 + n] = f2bf(v);
        } else {
          ((float*)out)[(size_t)m * (size_t)N + n] = v;
        }
      }
    }
  }
}

// ---------------- converters ----------------
__global__ void cvt_bf_kernel(const float* __restrict__ in, u16* __restrict__ out, int n) {
  int i = ((int)blockIdx.x * 256 + (int)threadIdx.x) * 8;
  if (i + 8 <= n) {
    float4 a = *(const float4*)(in + i);
    float4 b = *(const float4*)(in + i + 4);
    union { u16 o[8]; uint4 q; } u;
    u.o[0] = f2bf(a.x); u.o[1] = f2bf(a.y); u.o[2] = f2bf(a.z); u.o[3] = f2bf(a.w);
    u.o[4] = f2bf(b.x); u.o[5] = f2bf(b.y); u.o[6] = f2bf(b.z); u.o[7] = f2bf(b.w);
    *(uint4*)(out + i) = u.q;
  } else {
    for (int k = i; k < n; ++k) out[k] = f2bf(in[k]);
  }
}

__global__ void h0cvt_kernel(const float* __restrict__ h0, float* __restrict__ h_f32,
                             u16* __restrict__ h_bf, int layer) {
  int i = (int)blockIdx.x * 256 + (int)threadIdx.x;  // 0..32767
  if (i < 32768) {
    int b = i >> 10, j = i & 1023;
    float v = h0[b * 2048 + layer * 1024 + j];
    h_f32[i] = v;
    h_bf[i] = f2bf(v);
  }
}

// ---------------- host ----------------
extern "C" void kernel_launch(void* const* d_in, const int* in_sizes, int n_in,
                              void* d_out, int out_size, void* d_ws, size_t ws_size,
                              hipStream_t stream) {
  const float* x   = (const float*)d_in[0];  // [32][512][1024]
  const float* h0  = (const float*)d_in[1];  // [32][2][1024]
  const float* Wx  = (const float*)d_in[2];  // [2][3072][1024]
  const float* bx  = (const float*)d_in[3];  // [2][3072]
  const float* Wh  = (const float*)d_in[4];  // [2][3072][1024]
  const float* Why = (const float*)d_in[5];  // [1024][1024]
  const float* bhy = (const float*)d_in[6];  // [1024]
  float* out = (float*)d_out;
  float* hidden = out + (size_t)32 * 512 * 1024;

  char* ws = (char*)d_ws;
  u16* xproj = (u16*)ws;  ws += (size_t)512 * 32 * 3072 * 2;   // 100.7 MB
  u16* ysb   = (u16*)ws;  ws += (size_t)32 * 512 * 1024 * 2;   // 33.6 MB
  u16* xbf   = (u16*)ws;  ws += (size_t)32 * 512 * 1024 * 2;   // 33.6 MB
  u16* Wxb   = (u16*)ws;  ws += (size_t)2 * 3072 * 1024 * 2;   // 12.6 MB
  u16* Whb   = (u16*)ws;  ws += (size_t)2 * 3072 * 1024 * 2;   // 12.6 MB
  u16* Whyb  = (u16*)ws;  ws += (size_t)1024 * 1024 * 2;       // 2.1 MB
  u16* h_bf  = (u16*)ws;  ws += 65536;
  u16* rh_bf = (u16*)ws;  ws += 65536;
  float* h_f32 = (float*)ws; ws += 131072;
  float* z_f32 = (float*)ws; ws += 131072;
  int* bar = (int*)ws;    ws += 256;

  cvt_bf_kernel<<<(32 * 512 * 1024 / 8 + 255) / 256, 256, 0, stream>>>(x, xbf, 32 * 512 * 1024);
  cvt_bf_kernel<<<(2 * 3072 * 1024 / 8 + 255) / 256, 256, 0, stream>>>(Wx, Wxb, 2 * 3072 * 1024);
  cvt_bf_kernel<<<(2 * 3072 * 1024 / 8 + 255) / 256, 256, 0, stream>>>(Wh, Whb, 2 * 3072 * 1024);
  cvt_bf_kernel<<<(1024 * 1024 / 8 + 255) / 256, 256, 0, stream>>>(Why, Whyb, 1024 * 1024);

  // layer 0
  gemm_bt_kernel<0><<<dim3(3072 / 128, 16384 / 128), 256, 0, stream>>>(
      xbf, Wxb, bx, (void*)xproj, 16384, 3072, 1024);
  hipMemsetAsync(bar, 0, 256, stream);
  h0cvt_kernel<<<128, 256, 0, stream>>>(h0, h_f32, h_bf, 0);
  gru_rec_kernel<<<48, 256, 0, stream>>>(xproj, Whb, h_bf, h_f32, rh_bf, z_f32,
                                         ysb, hidden, 0, bar);
  // layer 1
  gemm_bt_kernel<0><<<dim3(3072 / 128, 16384 / 128), 256, 0, stream>>>(
      ysb, Wxb + (size_t)3072 * 1024, bx + 3072, (void*)xproj, 16384, 3072, 1024);
  hipMemsetAsync(bar, 0, 256, stream);
  h0cvt_kernel<<<128, 256, 0, stream>>>(h0, h_f32, h_bf, 1);
  gru_rec_kernel<<<48, 256, 0, stream>>>(xproj, Whb + (size_t)3072 * 1024, h_bf, h_f32,
                                         rh_bf, z_f32, ysb, hidden, 1, bar);
  // output projection
  gemm_bt_kernel<1><<<dim3(1024 / 128, 16384 / 128), 256, 0, stream>>>(
      ysb, Whyb, bhy, (void*)out, 16384, 1024, 1024);
}

// Round 2
// 12701.465 us; speedup vs baseline: 1.2923x; 1.2923x over previous
//
#include <hip/hip_runtime.h>
#include <stdint.h>

// B=32, S=512, I=H=O=1024, L=2.  All inputs f32; compute in bf16 MFMA + f32 accum.

typedef __bf16 bf16x8 __attribute__((ext_vector_type(8)));
typedef float f32x4 __attribute__((ext_vector_type(4)));
typedef unsigned short u16;
typedef unsigned int u32;

typedef __attribute__((address_space(1))) u32 as1_u32;
typedef __attribute__((address_space(3))) u32 as3_u32;

__device__ __forceinline__ u16 f2bf(float f) {
  union { float f; u32 u; } a; a.f = f;
  u32 u = a.u;
  u32 r = (u + 0x7fffu + ((u >> 16) & 1u)) >> 16;  // RNE
  return (u16)r;
}
__device__ __forceinline__ float bf2f(u16 b) {
  union { u32 u; float f; } a; a.u = ((u32)b) << 16;
  return a.f;
}
__device__ __forceinline__ float sigmoidf_(float x) {
  return 1.0f / (1.0f + __expf(-x));
}
__device__ __forceinline__ bf16x8 as_bf(uint4 q) {
  union { uint4 q; bf16x8 v; } u; u.q = q; return u.v;
}

#define MFMA16(a, b, c) __builtin_amdgcn_mfma_f32_16x16x32_bf16((a), (b), (c), 0, 0, 0)

// async global->LDS, 16B per lane; lds dest = wave-uniform base + lane*16
__device__ __forceinline__ void gll16(const void* g, void* l) {
  __builtin_amdgcn_global_load_lds((as1_u32*)g, (as3_u32*)l, 16, 0, 0);
}

// ---------------- per-wg flag sync (no RMW contention) ----------------
// producer wg w: flags[w] = step+1 (release).  consumer: lanes poll flags in
// parallel, __all() combine, then one acquire fence.
__device__ __forceinline__ void signal_flag(int* flag, int val) {
  __syncthreads();  // all waves' stores drained (vmcnt=0 before s_barrier)
  if (threadIdx.x == 0) {
    __builtin_amdgcn_fence(__ATOMIC_RELEASE, "agent");
    __hip_atomic_store(flag, val, __ATOMIC_RELAXED, __HIP_MEMORY_SCOPE_AGENT);
  }
}
__device__ __forceinline__ void wait_flags(int* flags, int nf, int target, int tid) {
  if (tid < 64) {
    int i = tid;
    for (;;) {
      int v = (i < nf)
                  ? __hip_atomic_load(&flags[i], __ATOMIC_RELAXED, __HIP_MEMORY_SCOPE_AGENT)
                  : target;
      if (__all(v >= target)) break;
      __builtin_amdgcn_s_sleep(1);
    }
    __builtin_amdgcn_fence(__ATOMIC_ACQUIRE, "agent");
  }
  __syncthreads();
}

// Stage a [32][1024] bf16 matrix (64 KB) global->LDS with 512 threads (8 waves).
// LDS chunk (row, sc) <- global chunk (row, sc ^ (row&7))  (16B chunks).
__device__ __forceinline__ void stage32x1024(const u16* g, u16* lds, int tid) {
  const int lane = tid & 63, wv = tid >> 6;
#pragma unroll
  for (int it = 0; it < 8; ++it) {
    int base = wv * 512 + it * 64;  // chunk index for lane 0 (wave-uniform)
    int ub = __builtin_amdgcn_readfirstlane(base);
    int c = base + lane;
    int row = c >> 7, sc = c & 127;
    int gsc = sc ^ (row & 7);
    gll16((const char*)g + (size_t)(row * 128 + gsc) * 16, (char*)lds + (size_t)ub * 16);
  }
}
// read one MFMA A-fragment (16B) for logical (row, chunk cc=kt*4+hi4) from swizzled LDS
__device__ __forceinline__ uint4 read_frag_sw(const u16* lds, int row, int kt, int hi4) {
  int cc = kt * 4 + hi4;
  int sc = cc ^ (row & 7);
  return *(const uint4*)((const char*)lds + (size_t)row * 2048 + (size_t)sc * 16);
}

__device__ __forceinline__ void load_xpv(float* xpv, const u16* xproj, int s, int n_g, int hi4) {
  const u16* xb = xproj + (size_t)s * (32 * 3072) + n_g;
#pragma unroll
  for (int r = 0; r < 8; ++r) {
    int b = hi4 * 4 + (r & 3) + ((r >> 2) << 4);
    xpv[r] = bf2f(xb[(size_t)b * 3072]);
  }
}

// ---------------- persistent GRU recurrence (one layer, 512 steps) ----------------
// grid = 24 wg x 512 thr (8 waves).  gw = wg*8+wv in [0,192): Wh rows [gw*16, gw*16+16).
//   wg 0..7  : z   (Wh rows    0..1023)
//   wg 8..15 : r   (rows 1024..2047)
//   wg 16..23: g   (rows 2048..3071)
// step s: phase1 (z/r wgs): pre = h @ W^T; z->z_f32 | rh=r*h(LDS) -> rh_bf; signal A[wg].
//         phase2 (g wgs): wait A; pre = rh @ Whg^T; h'=z*h_reg+(1-z)*g; h_bf store;
//                         signal B[wg-16]; ys/hidden stores off critical path.
//         z/r wgs wait B before next step.
__global__ __launch_bounds__(512, 1) void gru_rec_kernel(
    const u16* __restrict__ xproj,  // [512][32][3072] bf16
    const u16* __restrict__ Whl,    // [3072][1024] bf16 (this layer)
    const float* __restrict__ h0,   // [32][2][1024] f32 (original input)
    u16* __restrict__ h_bf,         // [32][1024]
    u16* __restrict__ rh_bf,        // [32][1024]
    float* __restrict__ z_f32,      // [32][1024]
    u16* __restrict__ ys,           // [32][512][1024]
    float* __restrict__ hidden,     // [32][2][1024] (d_out tail)
    int layer,
    int* __restrict__ bar)          // flagsA = bar[0..15], flagsB = bar[32..39] (pre-zeroed)
{
  __shared__ u16 smem[32 * 1024];  // 64 KB staging (h or rh)
  const int tid = (int)threadIdx.x;
  const int lane = tid & 63;
  const int wv = tid >> 6;
  const int wg = (int)blockIdx.x;
  const int gw = wg * 8 + wv;
  const int col = lane & 15;       // B-frag column (gate slice) / A row
  const int hi4 = lane >> 4;       // 0..3
  const int n_g = gw * 16 + col;   // global gate index in [0,3072)

  int* flagsA = bar;
  int* flagsB = bar + 32;

  // persistent B fragments: 32 k-iters x 16B = 128 VGPRs
  uint4 Bf[32];
  {
    const u16* wrow = Whl + (size_t)n_g * 1024 + 8 * hi4;
#pragma unroll
    for (int kt = 0; kt < 32; ++kt) Bf[kt] = *(const uint4*)(wrow + kt * 32);
  }

  if (wg < 16) {
    // ================= phase-1 workgroups (z: wg<8, r: wg>=8) =================
    const bool is_z = (wg < 8);
    const int rc = n_g - 1024;  // valid for r only
    float xpv[8];
    load_xpv(xpv, xproj, 0, n_g, hi4);
    for (int s = 0; s < 512; ++s) {
      stage32x1024(h_bf, smem, tid);
      __syncthreads();
      f32x4 acc0 = {0.f, 0.f, 0.f, 0.f}, acc1 = {0.f, 0.f, 0.f, 0.f};
#pragma unroll
      for (int kt = 0; kt < 32; ++kt) {
        bf16x8 b = as_bf(Bf[kt]);
        uint4 a0 = read_frag_sw(smem, col, kt, hi4);
        uint4 a1 = read_frag_sw(smem, col + 16, kt, hi4);
        acc0 = MFMA16(as_bf(a0), b, acc0);
        acc1 = MFMA16(as_bf(a1), b, acc1);
      }
      if (is_z) {
#pragma unroll
        for (int r = 0; r < 8; ++r) {
          int b = hi4 * 4 + (r & 3) + ((r >> 2) << 4);
          float pre = (r < 4) ? acc0[r & 3] : acc1[r & 3];
          z_f32[b * 1024 + n_g] = sigmoidf_(xpv[r] + pre);
        }
      } else {
#pragma unroll
        for (int r = 0; r < 8; ++r) {
          int b = hi4 * 4 + (r & 3) + ((r >> 2) << 4);
          float pre = (r < 4) ? acc0[r & 3] : acc1[r & 3];
          float rv = sigmoidf_(xpv[r] + pre);
          // h[b][rc] from the swizzled LDS copy we just staged
          u16 hraw = smem[b * 1024 + ((((rc >> 3) ^ (b & 7)) << 3) | (rc & 7))];
          rh_bf[b * 1024 + rc] = f2bf(rv * bf2f(hraw));
        }
      }
      signal_flag(&flagsA[wg], s + 1);
      if (s < 511) {
        load_xpv(xpv, xproj, s + 1, n_g, hi4);   // prefetch (const data, pre-fence ok)
        wait_flags(flagsB, 8, s + 1, tid);       // h(s) ready
      }
    }
  } else {
    // ================= phase-2 workgroups (g / h-update) =================
    const int gc = n_g - 2048;
    float h_reg[8];
#pragma unroll
    for (int r = 0; r < 8; ++r) {
      int b = hi4 * 4 + (r & 3) + ((r >> 2) << 4);
      h_reg[r] = h0[b * 2048 + layer * 1024 + gc];
    }
    for (int s = 0; s < 512; ++s) {
      float xpv[8];
      load_xpv(xpv, xproj, s, n_g, hi4);   // prefetch before wait
      wait_flags(flagsA, 16, s + 1, tid);  // z, rh ready
      stage32x1024(rh_bf, smem, tid);
      __syncthreads();
      f32x4 acc0 = {0.f, 0.f, 0.f, 0.f}, acc1 = {0.f, 0.f, 0.f, 0.f};
#pragma unroll
      for (int kt = 0; kt < 32; ++kt) {
        bf16x8 b = as_bf(Bf[kt]);
        uint4 a0 = read_frag_sw(smem, col, kt, hi4);
        uint4 a1 = read_frag_sw(smem, col + 16, kt, hi4);
        acc0 = MFMA16(as_bf(a0), b, acc0);
        acc1 = MFMA16(as_bf(a1), b, acc1);
      }
      u16 hb[8];
#pragma unroll
      for (int r = 0; r < 8; ++r) {
        int b = hi4 * 4 + (r & 3) + ((r >> 2) << 4);
        float pre = (r < 4) ? acc0[r & 3] : acc1[r & 3];
        float gv = sigmoidf_(xpv[r] + pre);
        float zv = z_f32[b * 1024 + gc];
        float hn = zv * h_reg[r] + (1.0f - zv) * gv;
        h_reg[r] = hn;
        hb[r] = f2bf(hn);
        h_bf[b * 1024 + gc] = hb[r];
      }
      signal_flag(&flagsB[wg - 16], s + 1);
      // off-critical-path stores (consumed only after this kernel ends)
#pragma unroll
      for (int r = 0; r < 8; ++r) {
        int b = hi4 * 4 + (r & 3) + ((r >> 2) << 4);
        ys[(size_t)b * (512 * 1024) + (size_t)s * 1024 + gc] = hb[r];
      }
      if (s == 511) {
#pragma unroll
        for (int r = 0; r < 8; ++r) {
          int b = hi4 * 4 + (r & 3) + ((r >> 2) << 4);
          hidden[b * 2048 + layer * 1024 + gc] = h_reg[r];
        }
      }
    }
  }
}

// ---------------- 128x128-tile bf16 GEMM: C[m,n] = sum_k A[m,k]*W[n,k] + bias[n] ----------------
// MODE 0: bf16 out to xproj layout [s][b][3072] with m = b*512+s
// MODE 1: f32 out, linear [m][N]
template <int MODE>
__global__ __launch_bounds__(256, 1) void gemm_bt_kernel(
    const u16* __restrict__ A, const u16* __restrict__ W,
    const float* __restrict__ bias, void* __restrict__ out,
    int M, int N, int K)
{
  __shared__ u16 At[128 * 32];
  __shared__ u16 Wt[128 * 32];
  const int tid = threadIdx.x;
  const int lane = tid & 63, wv = tid >> 6;
  const int wr = wv >> 1, wc = wv & 1;
  const int m0 = (int)blockIdx.y * 128, n0 = (int)blockIdx.x * 128;
  const int col = lane & 15, hi4 = lane >> 4;
  const size_t K2 = (size_t)K * 2;

  f32x4 acc[4][4];
#pragma unroll
  for (int i = 0; i < 4; ++i)
#pragma unroll
    for (int j = 0; j < 4; ++j) acc[i][j] = (f32x4){0.f, 0.f, 0.f, 0.f};

  const int nkt = K >> 5;
  for (int kt = 0; kt < nkt; ++kt) {
    __syncthreads();
#pragma unroll
    for (int it = 0; it < 2; ++it) {
      int cb = wv * 128 + it * 64;
      int ub = __builtin_amdgcn_readfirstlane(cb);
      int c = cb + lane;
      int row = c >> 2, slot = c & 3;
      int koff = (slot ^ ((row >> 1) & 3)) * 16;  // swizzled source -> linear LDS
      gll16((const char*)A + (size_t)(m0 + row) * K2 + (size_t)kt * 64 + koff,
            (char*)At + (size_t)ub * 16);
      gll16((const char*)W + (size_t)(n0 + row) * K2 + (size_t)kt * 64 + koff,
            (char*)Wt + (size_t)ub * 16);
    }
    __syncthreads();
    uint4 Af[4], Wf[4];
#pragma unroll
    for (int i = 0; i < 4; ++i) {
      int row = wr * 64 + i * 16 + col;
      int sc = hi4 ^ ((row >> 1) & 3);
      Af[i] = *(const uint4*)((const char*)At + (size_t)row * 64 + (size_t)sc * 16);
    }
#pragma unroll
    for (int j = 0; j < 4; ++j) {
      int row = wc * 64 + j * 16 + col;
      int sc = hi4 ^ ((row >> 1) & 3);
      Wf[j] = *(const uint4*)((const char*)Wt + (size_t)row * 64 + (size_t)sc * 16);
    }
#pragma unroll
    for (int i = 0; i < 4; ++i)
#pragma unroll
      for (int j = 0; j < 4; ++j)
        acc[i][j] = MFMA16(as_bf(Af[i]), as_bf(Wf[j]), acc[i][j]);
  }
  // epilogue: D[row=4*hi4+jj][col] per 16x16
#pragma unroll
  for (int i = 0; i < 4; ++i) {
#pragma unroll
    for (int j = 0; j < 4; ++j) {
      int n = n0 + wc * 64 + j * 16 + col;
      float bv = bias[n];
#pragma unroll
      for (int jj = 0; jj < 4; ++jj) {
        int m = m0 + wr * 64 + i * 16 + hi4 * 4 + jj;
        float v = acc[i][j][jj] + bv;
        if (MODE == 0) {
          ((u16*)out)[(size_t)(m & 511) * (32 * 3072) + (size_t)(m >> 9) * 3072 + n] = f2bf(v);
        } else {
          ((float*)out)[(size_t)m * (size_t)N + n] = v;
        }
      }
    }
  }
}

// ---------------- converters ----------------
__global__ void cvt_bf_kernel(const float* __restrict__ in, u16* __restrict__ out, int n) {
  int i = ((int)blockIdx.x * 256 + (int)threadIdx.x) * 8;
  if (i + 8 <= n) {
    float4 a = *(const float4*)(in + i);
    float4 b = *(const float4*)(in + i + 4);
    union { u16 o[8]; uint4 q; } u;
    u.o[0] = f2bf(a.x); u.o[1] = f2bf(a.y); u.o[2] = f2bf(a.z); u.o[3] = f2bf(a.w);
    u.o[4] = f2bf(b.x); u.o[5] = f2bf(b.y); u.o[6] = f2bf(b.z); u.o[7] = f2bf(b.w);
    *(uint4*)(out + i) = u.q;
  } else {
    for (int k = i; k < n; ++k) out[k] = f2bf(in[k]);
  }
}

__global__ void h0cvt_kernel(const float* __restrict__ h0, u16* __restrict__ h_bf, int layer) {
  int i = (int)blockIdx.x * 256 + (int)threadIdx.x;  // 0..32767
  if (i < 32768) {
    int b = i >> 10, j = i & 1023;
    h_bf[i] = f2bf(h0[b * 2048 + layer * 1024 + j]);
  }
}

// ---------------- host ----------------
extern "C" void kernel_launch(void* const* d_in, const int* in_sizes, int n_in,
                              void* d_out, int out_size, void* d_ws, size_t ws_size,
                              hipStream_t stream) {
  const float* x   = (const float*)d_in[0];  // [32][512][1024]
  const float* h0  = (const float*)d_in[1];  // [32][2][1024]
  const float* Wx  = (const float*)d_in[2];  // [2][3072][1024]
  const float* bx  = (const float*)d_in[3];  // [2][3072]
  const float* Wh  = (const float*)d_in[4];  // [2][3072][1024]
  const float* Why = (const float*)d_in[5];  // [1024][1024]
  const float* bhy = (const float*)d_in[6];  // [1024]
  float* out = (float*)d_out;
  float* hidden = out + (size_t)32 * 512 * 1024;

  char* ws = (char*)d_ws;
  u16* xproj = (u16*)ws;  ws += (size_t)512 * 32 * 3072 * 2;   // 100.7 MB
  u16* ysb   = (u16*)ws;  ws += (size_t)32 * 512 * 1024 * 2;   // 33.6 MB
  u16* xbf   = (u16*)ws;  ws += (size_t)32 * 512 * 1024 * 2;   // 33.6 MB
  u16* Wxb   = (u16*)ws;  ws += (size_t)2 * 3072 * 1024 * 2;   // 12.6 MB
  u16* Whb   = (u16*)ws;  ws += (size_t)2 * 3072 * 1024 * 2;   // 12.6 MB
  u16* Whyb  = (u16*)ws;  ws += (size_t)1024 * 1024 * 2;       // 2.1 MB
  u16* h_bf  = (u16*)ws;  ws += 65536;
  u16* rh_bf = (u16*)ws;  ws += 65536;
  float* z_f32 = (float*)ws; ws += 131072;
  int* bar = (int*)ws;    ws += 256;

  cvt_bf_kernel<<<(32 * 512 * 1024 / 8 + 255) / 256, 256, 0, stream>>>(x, xbf, 32 * 512 * 1024);
  cvt_bf_kernel<<<(2 * 3072 * 1024 / 8 + 255) / 256, 256, 0, stream>>>(Wx, Wxb, 2 * 3072 * 1024);
  cvt_bf_kernel<<<(2 * 3072 * 1024 / 8 + 255) / 256, 256, 0, stream>>>(Wh, Whb, 2 * 3072 * 1024);
  cvt_bf_kernel<<<(1024 * 1024 / 8 + 255) / 256, 256, 0, stream>>>(Why, Whyb, 1024 * 1024);

  // layer 0
  gemm_bt_kernel<0><<<dim3(3072 / 128, 16384 / 128), 256, 0, stream>>>(
      xbf, Wxb, bx, (void*)xproj, 16384, 3072, 1024);
  hipMemsetAsync(bar, 0, 256, stream);
  h0cvt_kernel<<<128, 256, 0, stream>>>(h0, h_bf, 0);
  gru_rec_kernel<<<24, 512, 0, stream>>>(xproj, Whb, h0, h_bf, rh_bf, z_f32,
                                         ysb, hidden, 0, bar);
  // layer 1
  gemm_bt_kernel<0><<<dim3(3072 / 128, 16384 / 128), 256, 0, stream>>>(
      ysb, Wxb + (size_t)3072 * 1024, bx + 3072, (void*)xproj, 16384, 3072, 1024);
  hipMemsetAsync(bar, 0, 256, stream);
  h0cvt_kernel<<<128, 256, 0, stream>>>(h0, h_bf, 1);
  gru_rec_kernel<<<24, 512, 0, stream>>>(xproj, Whb + (size_t)3072 * 1024, h0, h_bf,
                                         rh_bf, z_f32, ysb, hidden, 1, bar);
  // output projection
  gemm_bt_kernel<1><<<dim3(1024 / 128, 16384 / 128), 256, 0, stream>>>(
      ysb, Whyb, bhy, (void*)out, 16384, 1024, 1024);
}